// Round 6
// baseline (516.372 us; speedup 1.0000x reference)
//
#include <hip/hip_runtime.h>
#include <hip/hip_bf16.h>
#include <stdint.h>

#define BATCH 8
#define SEQ   4096
#define DM    512
#define HD    120

typedef __bf16   v8bf  __attribute__((ext_vector_type(8)));
typedef float    v16f  __attribute__((ext_vector_type(16)));
typedef int      i4    __attribute__((ext_vector_type(4)));
typedef uint32_t u32x2 __attribute__((ext_vector_type(2)));
typedef uint32_t u32x4 __attribute__((ext_vector_type(4)));
typedef float    f32x4 __attribute__((ext_vector_type(4)));

static __device__ __forceinline__ ushort f2bf(float x) {
  uint32_t u = __builtin_bit_cast(uint32_t, x);
  return (ushort)((u + 0x7fffu + ((u >> 16) & 1u)) >> 16);
}

// -------------------------------------------------------------------------
// prep_kernel, grid 1536 x 256 thr. bid%3==0 (512 blocks): ctx GEMM (f32
// VALU, LINEAR bf16 output [B*S][128], cols 120..127 zero). Other 1024
// blocks: compress 32 mask rows -> 1 bit/elem. Interleaved for co-residency
// (mask HBM stream overlaps GEMM VALU).
// -------------------------------------------------------------------------
__global__ __launch_bounds__(256) void prep_kernel(
    const float* __restrict__ q, const float* __restrict__ wq,
    const float* __restrict__ bq, const float* __restrict__ wt,
    const int* __restrict__ mask, ushort* __restrict__ ctx,
    uint32_t* __restrict__ bits)
{
  __shared__ __align__(16) float qs[32][68];    // [kk][row]
  __shared__ __align__(16) float ws2[32][136];  // [kk][col]

  const int t = threadIdx.x;

  if (blockIdx.x % 3 != 0) {
    // ---- mask compression: 32 rows ----
    const int cb = blockIdx.x - blockIdx.x / 3 - 1;   // 0..1023
    const size_t row0 = (size_t)cb * 32;
    const int rhalf = t >> 7;            // 0..1
    const int pw    = t & 127;           // 32-bit word within row
    const int* mbase = mask + row0 * SEQ;
    uint32_t* bbase  = bits + row0 * 128;
    for (int s = 0; s < 16; ++s) {
      int row = s * 2 + rhalf;
      const int* mp = mbase + (size_t)row * SEQ + pw * 32;
      uint32_t wd = 0;
      #pragma unroll
      for (int k = 0; k < 8; ++k) {
        i4 m = *(const i4*)(mp + k * 4);
        wd |= (uint32_t)(m.x != 0) << (k * 4);
        wd |= (uint32_t)(m.y != 0) << (k * 4 + 1);
        wd |= (uint32_t)(m.z != 0) << (k * 4 + 2);
        wd |= (uint32_t)(m.w != 0) << (k * 4 + 3);
      }
      bbase[(size_t)row * 128 + pw] = wd;
    }
    return;
  }

  // ---- ctx GEMM: rows gb*64 .. +63 ----
  const int gb = blockIdx.x / 3;                 // 0..511
  const int tx = t & 31, ty = t >> 5;
  const size_t row0 = (size_t)gb * 64;
  const int qr = t >> 2, qk = (t & 3) * 8;

  float acc[8][4];
  #pragma unroll
  for (int j = 0; j < 8; ++j)
    #pragma unroll
    for (int i = 0; i < 4; ++i) acc[j][i] = 0.f;

  for (int k0 = 0; k0 < DM; k0 += 32) {
    __syncthreads();
    {
      f32x4 v0 = *(const f32x4*)&q[(row0 + qr) * DM + k0 + qk];
      f32x4 v1 = *(const f32x4*)&q[(row0 + qr) * DM + k0 + qk + 4];
      #pragma unroll
      for (int i = 0; i < 4; ++i) qs[qk + i][qr] = v0[i];
      #pragma unroll
      for (int i = 0; i < 4; ++i) qs[qk + 4 + i][qr] = v1[i];
    }
    #pragma unroll
    for (int i = 0; i < 16; ++i) {
      int flat = t + i * 256;
      int kk = flat & 31, c = flat >> 5;
      ws2[kk][c] = (c < HD) ? wq[c * DM + k0 + kk] : 0.f;
    }
    __syncthreads();
    #pragma unroll
    for (int kk = 0; kk < 32; ++kk) {
      f32x4 bv = *(const f32x4*)&ws2[kk][tx * 4];
      f32x4 a0 = *(const f32x4*)&qs[kk][ty * 8];
      f32x4 a1 = *(const f32x4*)&qs[kk][ty * 8 + 4];
      #pragma unroll
      for (int r = 0; r < 4; ++r)
        #pragma unroll
        for (int c = 0; c < 4; ++c) {
          acc[r][c]     = fmaf(a0[r], bv[c], acc[r][c]);
          acc[4 + r][c] = fmaf(a1[r], bv[c], acc[4 + r][c]);
        }
    }
  }

  float wtv[4], bqv[4];
  #pragma unroll
  for (int i = 0; i < 4; ++i) {
    int c = tx * 4 + i;
    wtv[i] = (c < HD) ? wt[c] : 0.f;
    bqv[i] = (c < HD) ? bq[c] : 0.f;
  }
  #pragma unroll
  for (int j = 0; j < 8; ++j) {
    int r = ty * 8 + j;
    float v[4]; float ss = 0.f;
    #pragma unroll
    for (int i = 0; i < 4; ++i) {
      v[i] = (acc[j][i] + bqv[i]) * wtv[i];
      ss = fmaf(v[i], v[i], ss);
    }
    #pragma unroll
    for (int xm = 1; xm < 32; xm <<= 1) ss += __shfl_xor(ss, xm, 64);
    float rinv = 1.f / fmaxf(sqrtf(ss), 1e-12f);
    uint32_t p0 = (uint32_t)f2bf(v[0] * rinv) | ((uint32_t)f2bf(v[1] * rinv) << 16);
    uint32_t p1 = (uint32_t)f2bf(v[2] * rinv) | ((uint32_t)f2bf(v[3] * rinv) << 16);
    u32x2 o = {p0, p1};
    *(u32x2*)((char*)ctx + (row0 + r) * 256 + tx * 8) = o;
  }
}

// -------------------------------------------------------------------------
// attn_kernel: 1024 blocks x 4 waves. Block = 32 q-rows; wave = p-quarter
// (1024 cols). Zero LDS staging, zero per-iter barriers: A-fragments read
// straight from L2 (ctx panel XCD-resident via bid&7). 32x32x16 MFMA,
// transposed D[p][q]: lane = one q-row (col=lane&31), 16 p-elems whose mask
// bits live in ONE u32 of the prepacked bit-mask. Fixed softmax max = 1.0.
// -------------------------------------------------------------------------
#define MFMA32(A, B, C) __builtin_amdgcn_mfma_f32_32x32x16_bf16(A, B, C, 0, 0, 0)
#define ZERO16 (v16f){0.f,0.f,0.f,0.f,0.f,0.f,0.f,0.f,0.f,0.f,0.f,0.f,0.f,0.f,0.f,0.f}

#define LDA(R, tt) do {                                                       \
  const char* _a = abase + (size_t)(tt) * 8192;                               \
  R[0] = *(const v8bf*)(_a);        R[1] = *(const v8bf*)(_a + 32);           \
  R[2] = *(const v8bf*)(_a + 64);   R[3] = *(const v8bf*)(_a + 96);           \
  R[4] = *(const v8bf*)(_a + 128);  R[5] = *(const v8bf*)(_a + 160);          \
  R[6] = *(const v8bf*)(_a + 192);  R[7] = *(const v8bf*)(_a + 224);          \
} while (0)

#define QKT32(R, acc) do {                                                    \
  acc = ZERO16;                                                               \
  acc = MFMA32(R[0], qf[0], acc);  acc = MFMA32(R[1], qf[1], acc);            \
  acc = MFMA32(R[2], qf[2], acc);  acc = MFMA32(R[3], qf[3], acc);            \
  acc = MFMA32(R[4], qf[4], acc);  acc = MFMA32(R[5], qf[5], acc);            \
  acc = MFMA32(R[6], qf[6], acc);  acc = MFMA32(R[7], qf[7], acc);            \
} while (0)

#define STEPA(R, BW) do {                                                     \
  v16f acc; QKT32(R, acc);                                                    \
  _Pragma("unroll")                                                           \
  for (int _rq = 0; _rq < 4; ++_rq)                                           \
    _Pragma("unroll")                                                         \
    for (int _i = 0; _i < 4; ++_i) {                                          \
      float _e = __expf(acc[_rq * 4 + _i] - 1.0f);                            \
      lsum += (((BW) >> (_rq * 8 + hi4 + _i)) & 1u) ? _e : 0.f;               \
    }                                                                         \
} while (0)

#define STEPB(R, BW, tt) do {                                                 \
  v16f acc; QKT32(R, acc);                                                    \
  _Pragma("unroll")                                                           \
  for (int _rq = 0; _rq < 4; ++_rq) {                                         \
    f32x4 _o;                                                                 \
    _Pragma("unroll")                                                         \
    for (int _i = 0; _i < 4; ++_i)                                            \
      _o[_i] = (((BW) >> (_rq * 8 + hi4 + _i)) & 1u)                          \
                 ? __expf(acc[_rq * 4 + _i] - 1.0f) * lir : 0.f;              \
    *(f32x4*)(orow + (tt) * 32 + _rq * 8) = _o;                               \
  }                                                                           \
} while (0)

__global__ __launch_bounds__(256) void attn_kernel(
    const ushort* __restrict__ ctx, const uint32_t* __restrict__ bits,
    float* __restrict__ out)
{
  __shared__ float lW[128];
  __shared__ float lfin[32];

  const int t    = threadIdx.x;
  const int b    = blockIdx.x & 7;              // batch -> XCD-pinned panel
  const int qg   = blockIdx.x >> 3;             // 0..127
  const int w    = t >> 6, lane = t & 63;
  const int q    = lane & 31, hi = lane >> 5;
  const int hi4  = hi * 4;
  const int q0   = qg * 32;
  const int P0   = w * 1024;                    // this wave's p-quarter

  const char* ctxb = (const char*)ctx + (size_t)b * SEQ * 256;
  const char* abase = ctxb + (size_t)(P0 + q) * 256 + hi * 16;
  const uint32_t* __restrict__ brow =
      bits + ((size_t)b * SEQ + q0 + q) * 128 + (P0 >> 5);
  float* __restrict__ orow =
      out + ((size_t)b * SEQ + q0 + q) * SEQ + P0 + hi4;

  // persistent Q fragments (B-operand): 8 k-chunks of row q0+q
  const char* qp = ctxb + (size_t)(q0 + q) * 256 + hi * 16;
  v8bf qf[8];
  #pragma unroll
  for (int kc = 0; kc < 8; ++kc) qf[kc] = *(const v8bf*)(qp + kc * 32);

  v8bf SA[8], SB[8];
  u32x4 BQc, BQn;
  float lsum = 0.f;

  // ---------------- PASS A: masked sum of exp(s-1) ----------------
  LDA(SA, 0); LDA(SB, 1);
  BQc = *(const u32x4*)(brow);
  for (int tt = 0; tt < 32; tt += 4) {
    if (tt + 4 < 32) BQn = *(const u32x4*)(brow + tt + 4);
    STEPA(SA, BQc[0]);  if (tt + 2 < 32) LDA(SA, tt + 2);
    STEPA(SB, BQc[1]);  if (tt + 3 < 32) LDA(SB, tt + 3);
    STEPA(SA, BQc[2]);  if (tt + 4 < 32) LDA(SA, tt + 4);
    STEPA(SB, BQc[3]);  if (tt + 5 < 32) LDA(SB, tt + 5);
    BQc = BQn;
  }

  // ---------------- l merge: hi-halves then 4 p-quarter waves ----------------
  lsum += __shfl_xor(lsum, 32, 64);
  if (lane < 32) lW[w * 32 + lane] = lsum;
  __syncthreads();
  if (t < 32) {
    float lf = lW[t] + lW[32 + t] + lW[64 + t] + lW[96 + t];
    lfin[t] = (lf > 0.f) ? (1.f / lf) : 0.f;
  }
  __syncthreads();
  const float lir = lfin[q];

  // ---------------- PASS B: recompute, scale, write ----------------
  LDA(SA, 0); LDA(SB, 1);
  BQc = *(const u32x4*)(brow);
  for (int tt = 0; tt < 32; tt += 4) {
    if (tt + 4 < 32) BQn = *(const u32x4*)(brow + tt + 4);
    STEPB(SA, BQc[0], tt);      if (tt + 2 < 32) LDA(SA, tt + 2);
    STEPB(SB, BQc[1], tt + 1);  if (tt + 3 < 32) LDA(SB, tt + 3);
    STEPB(SA, BQc[2], tt + 2);  if (tt + 4 < 32) LDA(SA, tt + 4);
    STEPB(SB, BQc[3], tt + 3);  if (tt + 5 < 32) LDA(SB, tt + 5);
    BQc = BQn;
  }
}

// -------------------------------------------------------------------------
extern "C" void kernel_launch(void* const* d_in, const int* in_sizes, int n_in,
                              void* d_out, int out_size, void* d_ws, size_t ws_size,
                              hipStream_t stream) {
  const float* query = (const float*)d_in[0];
  const int*   mask  = (const int*)d_in[1];
  const float* w_q   = (const float*)d_in[2];
  const float* b_q   = (const float*)d_in[3];
  const float* wt    = (const float*)d_in[4];
  float* out = (float*)d_out;

  ushort*   ctx  = (ushort*)d_ws;                              // 8 MB
  uint32_t* bits = (uint32_t*)((char*)d_ws + (16u << 20));     // +16 MB

  prep_kernel<<<dim3(1536), dim3(256), 0, stream>>>(query, w_q, b_q, wt, mask, ctx, bits);
  attn_kernel<<<dim3(1024), dim3(256), 0, stream>>>(ctx, bits, out);
}